// Round 10
// baseline (125.457 us; speedup 1.0000x reference)
//
#include <hip/hip_runtime.h>

namespace {

constexpr int N  = 50000;
constexpr int R  = 10;
constexpr int DD = 5;
constexpr int RN = R * N;        // 500000
constexpr int DN = DD * N;       // 250000
constexpr int E  = 10000000;
constexpr int EP = E / 2;        // edge pairs (int4 loads)
constexpr int EPH = EP / 2;      // per-stream half

// bitmask geometry
constexpr int ZB_BLOCKS = (DN + 255) / 256;          // 977
constexpr int ZB_WORDS  = ZB_BLOCKS * 256 / 32;      // 7816 u32 (31264 B)

// K1 partition: bits + psc seed (syn algebra) + neuron
constexpr int SEED_BLOCKS = (RN / 4 + 255) / 256;    // 489
constexpr int NEUR_BLOCKS = (N + 255) / 256;         // 196
constexpr int PRE_BLOCKS  = ZB_BLOCKS + SEED_BLOCKS + NEUR_BLOCKS;

// scatter: 512-thread blocks, 4 blocks/CU co-resident
constexpr int SC_BLOCK = 512;
constexpr int SC_GRID  = 1024;
constexpr int GS       = SC_GRID * SC_BLOCK;         // 524288

// ---------------------------------------------------------------------------
// K1: spike bitmask + psc_rise/psc outputs (seeded, pre-scatter) + neuron.
__global__ __launch_bounds__(256) void pre_kernel(
    const float*  __restrict__ z_buf,
    unsigned int* __restrict__ bits,
    const float4* __restrict__ inputs4,
    const float*  __restrict__ psc_rise,
    const float*  __restrict__ psc,
    const float*  __restrict__ syn_decay,
    const float*  __restrict__ psc_initial,
    const float*  __restrict__ v,
    const float*  __restrict__ r,
    const float*  __restrict__ asc1,
    const float*  __restrict__ asc2,
    const float*  __restrict__ v_th,
    const float*  __restrict__ e_l,
    const float*  __restrict__ v_reset,
    const float*  __restrict__ g,
    const float*  __restrict__ decay,
    const float*  __restrict__ current_factor,
    const float*  __restrict__ t_ref,
    const float2* __restrict__ k,
    const float2* __restrict__ asc_amps,
    const float*  __restrict__ voltage_scale,
    const float*  __restrict__ voltage_offset,
    float*        __restrict__ out)
{
    int b = blockIdx.x;
    int tid = threadIdx.x;

    if (b < ZB_BLOCKS) {
        int i = b * 256 + tid;
        float zv = (i < DN) ? z_buf[i] : 0.0f;
        unsigned long long m = __ballot(zv != 0.0f);
        if ((tid & 63) == 0) {
            int w = i >> 5;
            bits[w]     = (unsigned int)m;
            bits[w + 1] = (unsigned int)(m >> 32);
        }
        return;
    }
    b -= ZB_BLOCKS;
    if (b < SEED_BLOCKS) {
        int j = b * 256 + tid;
        if (j >= RN / 4) return;
        const float4* pr4 = reinterpret_cast<const float4*>(psc_rise);
        const float4* ps4 = reinterpret_cast<const float4*>(psc);
        const float4* sd4 = reinterpret_cast<const float4*>(syn_decay);
        const float4* pi4 = reinterpret_cast<const float4*>(psc_initial);
        float4* opr4 = reinterpret_cast<float4*>(out + 11 * N);
        float4* ops4 = reinterpret_cast<float4*>(out + 21 * N);
        float4 sd = sd4[j];
        float4 pr = pr4[j];
        float4 pi = pi4[j];
        float4 in = inputs4[j];
        float4 ps = ps4[j];
        float4 opr, ops;
        opr.x = sd.x * pr.x + in.x * pi.x;
        opr.y = sd.y * pr.y + in.y * pi.y;
        opr.z = sd.z * pr.z + in.z * pi.z;
        opr.w = sd.w * pr.w + in.w * pi.w;
        ops.x = ps.x * sd.x + sd.x * pr.x;
        ops.y = ps.y * sd.y + sd.y * pr.y;
        ops.z = ps.z * sd.z + sd.z * pr.z;
        ops.w = ps.w * sd.w + sd.w * pr.w;
        opr4[j] = opr;
        ops4[j] = ops;
        return;
    }
    b -= SEED_BLOCKS;
    {
        int n = b * 256 + tid;
        if (n >= N) return;

        float prev_z = z_buf[n];

        const float2* p2 = reinterpret_cast<const float2*>(psc + n * R);
        float ic = 0.0f;
#pragma unroll
        for (int t = 0; t < R / 2; ++t) {
            float2 pp = p2[t];
            ic += pp.x + pp.y;
        }

        float new_r = fmaxf(r[n] + prev_z * t_ref[n] - 1.0f, 0.0f);   // DT=1

        float2 kk = k[n];
        float2 aa = asc_amps[n];
        float s0 = 1.0f / (1.0f + expf(-kk.x));
        float s1 = 1.0f / (1.0f + expf(-kk.y));
        float a1_old = asc1[n];
        float a2_old = asc2[n];
        float new_a1 = expf(-s0) * a1_old + prev_z * aa.x;
        float new_a2 = expf(-s1) * a2_old + prev_z * aa.y;

        float el = e_l[n];
        float new_v = decay[n] * v[n]
                    + current_factor[n] * (ic + a1_old + a2_old + g[n] * el);

        float vth = v_th[n];
        float v_sc = (new_v - vth) / (vth - el);
        float nz = (v_sc > 0.0f) ? 1.0f : 0.0f;
        if (new_r > 0.0f) nz = 0.0f;
        if (nz > 0.5f) new_v = v_reset[n];

        out[0 * N + n]  = nz;
        out[1 * N + n]  = new_v * voltage_scale[n] + voltage_offset[n];
        out[2 * N + n]  = nz;
        out[7 * N + n]  = new_v;
        out[8 * N + n]  = new_r;
        out[9 * N + n]  = new_a1;
        out[10 * N + n] = new_a2;
    }
}

// ---------------------------------------------------------------------------
// PROBE 1: pure idx4 stream, x4 passes (pass 1 cold, 2-4 L3-warm).
// Identical grid/block/loop shape to the scatter; no LDS, no atomics.
__global__ __launch_bounds__(SC_BLOCK) void probe_stream(
    const int4* __restrict__ idx4, int* __restrict__ dummy)
{
    const int gid = blockIdx.x * SC_BLOCK + threadIdx.x;
    int s = 0;
    for (int pass = 0; pass < 4; ++pass) {
        for (int p = gid; p < EP; p += GS) {
            int4 a = idx4[p];
            s ^= a.x ^ a.y ^ a.z ^ a.w;
        }
        asm volatile("" ::: "memory");   // block cross-pass load CSE
    }
    dummy[gid] = s;
}

// ---------------------------------------------------------------------------
// PROBE 2: stream + LDS bitmask staging + bit tests, x4 passes. No atomics.
__global__ __launch_bounds__(SC_BLOCK) void probe_bits(
    const int4* __restrict__ idx4, const unsigned int* __restrict__ bits_g,
    int* __restrict__ dummy)
{
    __shared__ unsigned int bits[ZB_WORDS];
    {
        const uint4* src = reinterpret_cast<const uint4*>(bits_g);
        uint4* dst = reinterpret_cast<uint4*>(bits);
        for (int i = threadIdx.x; i < ZB_WORDS / 4; i += SC_BLOCK)
            dst[i] = src[i];
    }
    __syncthreads();

    const int gid = blockIdx.x * SC_BLOCK + threadIdx.x;
    int s = 0;
    for (int pass = 0; pass < 4; ++pass) {
        for (int p = gid; p < EP; p += GS) {
            int4 a = idx4[p];
            s ^= a.x ^ a.z;
            s += (int)((bits[a.y >> 5] >> (a.y & 31)) & 1u)
               + (int)((bits[a.w >> 5] >> (a.w & 31)) & 1u);
        }
        asm volatile("" ::: "memory");
    }
    dummy[gid] = s;
}

// ---------------------------------------------------------------------------
// K2: sparse scatter directly into out_psc_rise (r8 structure, unchanged):
//   out_psc_rise[row] += rec_w[e] * psc_initial[row]   iff bit(col)
__device__ __forceinline__ void edge_pair(
    const int4 a, int p, const unsigned int* bits,
    const float* __restrict__ rec_w, const float* __restrict__ pinit,
    float* __restrict__ opr)
{
    unsigned int w0 = bits[a.y >> 5];
    unsigned int w1 = bits[a.w >> 5];
    if ((w0 >> (a.y & 31)) & 1u)
        atomicAdd(opr + a.x, rec_w[2 * p] * pinit[a.x]);
    if ((w1 >> (a.w & 31)) & 1u)
        atomicAdd(opr + a.z, rec_w[2 * p + 1] * pinit[a.z]);
}

__global__ __launch_bounds__(SC_BLOCK) void scatter_kernel(
    const float* __restrict__ rec_w,
    const int4*  __restrict__ idx4,          // [p] = (row0, col0, row1, col1)
    const unsigned int* __restrict__ bits_g,
    const float* __restrict__ pinit,
    const float* __restrict__ z_buf,
    float*       __restrict__ out)
{
    __shared__ unsigned int bits[ZB_WORDS];
    {
        const uint4* src = reinterpret_cast<const uint4*>(bits_g);
        uint4* dst = reinterpret_cast<uint4*>(bits);
        for (int i = threadIdx.x; i < ZB_WORDS / 4; i += SC_BLOCK)
            dst[i] = src[i];
    }
    __syncthreads();

    float* opr = out + 11 * N;

    const int gid = blockIdx.x * SC_BLOCK + threadIdx.x;

    int pA = gid, pB = gid + EPH;
    bool hA = pA < EPH;
    bool hB = pB < EP;
    int4 a = {0, 0, 0, 0}, b = {0, 0, 0, 0};
    if (hA) a = idx4[pA];
    if (hB) b = idx4[pB];
    while (hA || hB) {
        int nA = pA + GS, nB = pB + GS;
        bool hnA = hA && (nA < EPH);
        bool hnB = hB && (nB < EP);
        int4 na = {0, 0, 0, 0}, nb = {0, 0, 0, 0};
        if (hnA) na = idx4[nA];
        if (hnB) nb = idx4[nB];
        if (hA) edge_pair(a, pA, bits, rec_w, pinit, opr);
        if (hB) edge_pair(b, pB, bits, rec_w, pinit, opr);
        a = na; pA = nA; hA = hnA;
        b = nb; pB = nB; hB = hnB;
    }

    // tail: delay-buffer shift (independent of scatter results)
    {
        const float4* src = reinterpret_cast<const float4*>(z_buf);
        float4* dst = reinterpret_cast<float4*>(out + 3 * N);
        for (int i = gid; i < (DN - N) / 4; i += GS)
            dst[i] = src[i];
    }
}

} // namespace

extern "C" void kernel_launch(void* const* d_in, const int* in_sizes, int n_in,
                              void* d_out, int out_size, void* d_ws, size_t ws_size,
                              hipStream_t stream) {
    const float* inputs         = (const float*)d_in[0];
    const float* z_buf          = (const float*)d_in[1];
    const float* v              = (const float*)d_in[2];
    const float* r              = (const float*)d_in[3];
    const float* asc1           = (const float*)d_in[4];
    const float* asc2           = (const float*)d_in[5];
    const float* psc_rise       = (const float*)d_in[6];
    const float* psc            = (const float*)d_in[7];
    const float* rec_w          = (const float*)d_in[8];
    const int*   rec_idx        = (const int*)d_in[9];
    const float* v_th           = (const float*)d_in[10];
    const float* e_l            = (const float*)d_in[11];
    const float* v_reset        = (const float*)d_in[12];
    const float* g              = (const float*)d_in[13];
    const float* decay          = (const float*)d_in[14];
    const float* current_factor = (const float*)d_in[15];
    const float* t_ref          = (const float*)d_in[16];
    const float* k              = (const float*)d_in[17];
    const float* asc_amps       = (const float*)d_in[18];
    const float* syn_decay      = (const float*)d_in[19];
    const float* psc_initial    = (const float*)d_in[20];
    const float* voltage_scale  = (const float*)d_in[21];
    const float* voltage_offset = (const float*)d_in[22];

    float* out = (float*)d_out;
    unsigned int* bits = (unsigned int*)d_ws;                    // 31 KB
    int* dummy = (int*)((char*)d_ws + (4u << 20));               // 2 MB probe sink

    // K1: bits + seeded psc outputs + neuron (all scatter-independent)
    pre_kernel<<<PRE_BLOCKS, 256, 0, stream>>>(
        z_buf, bits, (const float4*)inputs, psc_rise, psc, syn_decay,
        psc_initial, v, r, asc1, asc2, v_th, e_l, v_reset, g, decay,
        current_factor, t_ref, (const float2*)k, (const float2*)asc_amps,
        voltage_scale, voltage_offset, out);

    // DIAGNOSTIC PROBES (x4 passes each so they rank in rocprof top-5)
    probe_stream<<<SC_GRID, SC_BLOCK, 0, stream>>>(
        (const int4*)rec_idx, dummy);
    probe_bits<<<SC_GRID, SC_BLOCK, 0, stream>>>(
        (const int4*)rec_idx, bits, dummy);

    // K2: real scatter (r8 structure, unchanged)
    scatter_kernel<<<SC_GRID, SC_BLOCK, 0, stream>>>(
        rec_w, (const int4*)rec_idx, bits, psc_initial, z_buf, out);
}

// Round 11
// 102.142 us; speedup vs baseline: 1.2283x; 1.2283x over previous
//
#include <hip/hip_runtime.h>

namespace {

constexpr int N  = 50000;
constexpr int R  = 10;
constexpr int DD = 5;
constexpr int RN = R * N;        // 500000
constexpr int DN = DD * N;       // 250000
constexpr int E  = 10000000;
constexpr int EP = E / 2;        // edge pairs (int4 loads)

// bitmask geometry
constexpr int ZB_BLOCKS = (DN + 255) / 256;          // 977
constexpr int ZB_WORDS  = ZB_BLOCKS * 256 / 32;      // 7816 u32 (31264 B)

// K1 partition: bits + psc seed (syn algebra) + neuron
constexpr int SEED_BLOCKS = (RN / 4 + 255) / 256;    // 489
constexpr int NEUR_BLOCKS = (N + 255) / 256;         // 196
constexpr int PRE_BLOCKS  = ZB_BLOCKS + SEED_BLOCKS + NEUR_BLOCKS;

// scatter: 512-thread blocks, 4 blocks/CU co-resident (31.3 KB LDS each)
constexpr int SC_BLOCK = 512;
constexpr int SC_GRID  = 1024;
constexpr int GS       = SC_GRID * SC_BLOCK;         // 524288

// ---------------------------------------------------------------------------
// K1: spike bitmask + psc_rise/psc outputs (seeded, pre-scatter) + neuron.
__global__ __launch_bounds__(256) void pre_kernel(
    const float*  __restrict__ z_buf,
    unsigned int* __restrict__ bits,
    const float4* __restrict__ inputs4,
    const float*  __restrict__ psc_rise,
    const float*  __restrict__ psc,
    const float*  __restrict__ syn_decay,
    const float*  __restrict__ psc_initial,
    const float*  __restrict__ v,
    const float*  __restrict__ r,
    const float*  __restrict__ asc1,
    const float*  __restrict__ asc2,
    const float*  __restrict__ v_th,
    const float*  __restrict__ e_l,
    const float*  __restrict__ v_reset,
    const float*  __restrict__ g,
    const float*  __restrict__ decay,
    const float*  __restrict__ current_factor,
    const float*  __restrict__ t_ref,
    const float2* __restrict__ k,
    const float2* __restrict__ asc_amps,
    const float*  __restrict__ voltage_scale,
    const float*  __restrict__ voltage_offset,
    float*        __restrict__ out)
{
    int b = blockIdx.x;
    int tid = threadIdx.x;

    if (b < ZB_BLOCKS) {
        int i = b * 256 + tid;
        float zv = (i < DN) ? z_buf[i] : 0.0f;
        unsigned long long m = __ballot(zv != 0.0f);
        if ((tid & 63) == 0) {
            int w = i >> 5;
            bits[w]     = (unsigned int)m;
            bits[w + 1] = (unsigned int)(m >> 32);
        }
        return;
    }
    b -= ZB_BLOCKS;
    if (b < SEED_BLOCKS) {
        int j = b * 256 + tid;
        if (j >= RN / 4) return;
        const float4* pr4 = reinterpret_cast<const float4*>(psc_rise);
        const float4* ps4 = reinterpret_cast<const float4*>(psc);
        const float4* sd4 = reinterpret_cast<const float4*>(syn_decay);
        const float4* pi4 = reinterpret_cast<const float4*>(psc_initial);
        float4* opr4 = reinterpret_cast<float4*>(out + 11 * N);
        float4* ops4 = reinterpret_cast<float4*>(out + 21 * N);
        float4 sd = sd4[j];
        float4 pr = pr4[j];
        float4 pi = pi4[j];
        float4 in = inputs4[j];
        float4 ps = ps4[j];
        float4 opr, ops;
        opr.x = sd.x * pr.x + in.x * pi.x;
        opr.y = sd.y * pr.y + in.y * pi.y;
        opr.z = sd.z * pr.z + in.z * pi.z;
        opr.w = sd.w * pr.w + in.w * pi.w;
        ops.x = ps.x * sd.x + sd.x * pr.x;
        ops.y = ps.y * sd.y + sd.y * pr.y;
        ops.z = ps.z * sd.z + sd.z * pr.z;
        ops.w = ps.w * sd.w + sd.w * pr.w;
        opr4[j] = opr;
        ops4[j] = ops;
        return;
    }
    b -= SEED_BLOCKS;
    {
        int n = b * 256 + tid;
        if (n >= N) return;

        float prev_z = z_buf[n];

        const float2* p2 = reinterpret_cast<const float2*>(psc + n * R);
        float ic = 0.0f;
#pragma unroll
        for (int t = 0; t < R / 2; ++t) {
            float2 pp = p2[t];
            ic += pp.x + pp.y;
        }

        float new_r = fmaxf(r[n] + prev_z * t_ref[n] - 1.0f, 0.0f);   // DT=1

        float2 kk = k[n];
        float2 aa = asc_amps[n];
        float s0 = 1.0f / (1.0f + expf(-kk.x));
        float s1 = 1.0f / (1.0f + expf(-kk.y));
        float a1_old = asc1[n];
        float a2_old = asc2[n];
        float new_a1 = expf(-s0) * a1_old + prev_z * aa.x;
        float new_a2 = expf(-s1) * a2_old + prev_z * aa.y;

        float el = e_l[n];
        float new_v = decay[n] * v[n]
                    + current_factor[n] * (ic + a1_old + a2_old + g[n] * el);

        float vth = v_th[n];
        float v_sc = (new_v - vth) / (vth - el);
        float nz = (v_sc > 0.0f) ? 1.0f : 0.0f;
        if (new_r > 0.0f) nz = 0.0f;
        if (nz > 0.5f) new_v = v_reset[n];

        out[0 * N + n]  = nz;
        out[1 * N + n]  = new_v * voltage_scale[n] + voltage_offset[n];
        out[2 * N + n]  = nz;
        out[7 * N + n]  = new_v;
        out[8 * N + n]  = new_r;
        out[9 * N + n]  = new_a1;
        out[10 * N + n] = new_a2;
    }
}

// ---------------------------------------------------------------------------
// PROBE: stream + bits + INLINE-dependent predicated gathers (no atomics),
// x4 passes. Isolates the gather cost that r8 paid inline.
__global__ __launch_bounds__(SC_BLOCK) void probe_active(
    const int4* __restrict__ idx4,
    const unsigned int* __restrict__ bits_g,
    const float* __restrict__ rec_w,
    const float* __restrict__ pinit,
    float* __restrict__ fdummy)
{
    __shared__ unsigned int bits[ZB_WORDS];
    {
        const uint4* src = reinterpret_cast<const uint4*>(bits_g);
        uint4* dst = reinterpret_cast<uint4*>(bits);
        for (int i = threadIdx.x; i < ZB_WORDS / 4; i += SC_BLOCK)
            dst[i] = src[i];
    }
    __syncthreads();

    const int gid = blockIdx.x * SC_BLOCK + threadIdx.x;
    float s = 0.0f;
    for (int pass = 0; pass < 4; ++pass) {
        for (int p = gid; p < EP; p += GS) {
            int4 a = idx4[p];
            if ((bits[a.y >> 5] >> (a.y & 31)) & 1u)
                s += rec_w[2 * p] * pinit[a.x];
            if ((bits[a.w >> 5] >> (a.w & 31)) & 1u)
                s += rec_w[2 * p + 1] * pinit[a.z];
        }
        asm volatile("" ::: "memory");
    }
    fdummy[gid] = s;
}

// ---------------------------------------------------------------------------
// K2: streaming scatter with ONE-ITERATION DEFERRED COMMIT.
// iter t: load idx4 (stream), commit iter t-1's pending atomics (gathers have
// a full iteration of slack -> HBM latency hidden), test bits, issue this
// iter's predicated gathers into registers.
__global__ __launch_bounds__(SC_BLOCK) void scatter_kernel(
    const float* __restrict__ rec_w,
    const int4*  __restrict__ idx4,          // [p] = (row0, col0, row1, col1)
    const unsigned int* __restrict__ bits_g,
    const float* __restrict__ pinit,
    const float* __restrict__ z_buf,
    float*       __restrict__ out)
{
    __shared__ unsigned int bits[ZB_WORDS];
    {
        const uint4* src = reinterpret_cast<const uint4*>(bits_g);
        uint4* dst = reinterpret_cast<uint4*>(bits);
        for (int i = threadIdx.x; i < ZB_WORDS / 4; i += SC_BLOCK)
            dst[i] = src[i];
    }
    __syncthreads();

    float* opr = out + 11 * N;
    const int gid = blockIdx.x * SC_BLOCK + threadIdx.x;

    bool  v0 = false, v1 = false;     // pending-commit state (prev iter)
    int   r0 = 0, r1 = 0;
    float w0 = 0.f, w1 = 0.f, q0 = 0.f, q1 = 0.f;

    for (int p = gid; p < EP; p += GS) {
        int4 a = idx4[p];             // stream load issues first

        // commit previous iteration's actives (gathers are ~1 iter old)
        if (v0) atomicAdd(opr + r0, w0 * q0);
        if (v1) atomicAdd(opr + r1, w1 * q1);

        bool a0 = (bits[a.y >> 5] >> (a.y & 31)) & 1u;
        bool a1 = (bits[a.w >> 5] >> (a.w & 31)) & 1u;
        r0 = a.x; r1 = a.z;
        if (a0) { w0 = rec_w[2 * p];     q0 = pinit[a.x]; }
        if (a1) { w1 = rec_w[2 * p + 1]; q1 = pinit[a.z]; }
        v0 = a0; v1 = a1;
    }
    // drain
    if (v0) atomicAdd(opr + r0, w0 * q0);
    if (v1) atomicAdd(opr + r1, w1 * q1);

    // tail: delay-buffer shift (independent of scatter results)
    {
        const float4* src = reinterpret_cast<const float4*>(z_buf);
        float4* dst = reinterpret_cast<float4*>(out + 3 * N);
        for (int i = gid; i < (DN - N) / 4; i += GS)
            dst[i] = src[i];
    }
}

} // namespace

extern "C" void kernel_launch(void* const* d_in, const int* in_sizes, int n_in,
                              void* d_out, int out_size, void* d_ws, size_t ws_size,
                              hipStream_t stream) {
    const float* inputs         = (const float*)d_in[0];
    const float* z_buf          = (const float*)d_in[1];
    const float* v              = (const float*)d_in[2];
    const float* r              = (const float*)d_in[3];
    const float* asc1           = (const float*)d_in[4];
    const float* asc2           = (const float*)d_in[5];
    const float* psc_rise       = (const float*)d_in[6];
    const float* psc            = (const float*)d_in[7];
    const float* rec_w          = (const float*)d_in[8];
    const int*   rec_idx        = (const int*)d_in[9];
    const float* v_th           = (const float*)d_in[10];
    const float* e_l            = (const float*)d_in[11];
    const float* v_reset        = (const float*)d_in[12];
    const float* g              = (const float*)d_in[13];
    const float* decay          = (const float*)d_in[14];
    const float* current_factor = (const float*)d_in[15];
    const float* t_ref          = (const float*)d_in[16];
    const float* k              = (const float*)d_in[17];
    const float* asc_amps       = (const float*)d_in[18];
    const float* syn_decay      = (const float*)d_in[19];
    const float* psc_initial    = (const float*)d_in[20];
    const float* voltage_scale  = (const float*)d_in[21];
    const float* voltage_offset = (const float*)d_in[22];

    float* out = (float*)d_out;
    unsigned int* bits = (unsigned int*)d_ws;                    // 31 KB
    float* fdummy = (float*)((char*)d_ws + (4u << 20));          // 2 MB sink

    // K1: bits + seeded psc outputs + neuron (all scatter-independent)
    pre_kernel<<<PRE_BLOCKS, 256, 0, stream>>>(
        z_buf, bits, (const float4*)inputs, psc_rise, psc, syn_decay,
        psc_initial, v, r, asc1, asc2, v_th, e_l, v_reset, g, decay,
        current_factor, t_ref, (const float2*)k, (const float2*)asc_amps,
        voltage_scale, voltage_offset, out);

    // DIAGNOSTIC: inline-dependent gather cost (no atomics), x4 passes
    probe_active<<<SC_GRID, SC_BLOCK, 0, stream>>>(
        (const int4*)rec_idx, bits, rec_w, psc_initial, fdummy);

    // K2: deferred-commit streaming scatter (+ shift tail)
    scatter_kernel<<<SC_GRID, SC_BLOCK, 0, stream>>>(
        rec_w, (const int4*)rec_idx, bits, psc_initial, z_buf, out);
}

// Round 12
// 31.810 us; speedup vs baseline: 3.9440x; 3.2110x over previous
//
#include <hip/hip_runtime.h>

namespace {

constexpr int N  = 50000;
constexpr int R  = 10;
constexpr int DD = 5;
constexpr int RN = R * N;        // 500000
constexpr int DN = DD * N;       // 250000
constexpr int E  = 10000000;
constexpr int EP = E / 2;        // edge pairs (int4 loads)

// bitmask geometry
constexpr int ZB_BLOCKS = (DN + 255) / 256;          // 977
constexpr int ZB_WORDS  = ZB_BLOCKS * 256 / 32;      // 7816 u32 (31264 B)

// K1 partition: bits + psc seed (syn algebra) + neuron
constexpr int SEED_BLOCKS = (RN / 4 + 255) / 256;    // 489
constexpr int NEUR_BLOCKS = (N + 255) / 256;         // 196
constexpr int PRE_BLOCKS  = ZB_BLOCKS + SEED_BLOCKS + NEUR_BLOCKS;

// scatter: 512-thread blocks, 4 blocks/CU co-resident (31.3 KB LDS each)
constexpr int SC_BLOCK = 512;
constexpr int SC_GRID  = 1024;
constexpr int GS       = SC_GRID * SC_BLOCK;         // 524288

// ---------------------------------------------------------------------------
// K1: spike bitmask + psc_rise/psc outputs (seeded, pre-scatter) + neuron.
//   out_psc_rise = syn_decay*psc_rise + inputs*psc_initial  (scatter adds
//                  rec_w*psc_initial on top atomically)
//   out_psc      = psc*syn_decay + syn_decay*psc_rise       (no i_rec dep)
__global__ __launch_bounds__(256) void pre_kernel(
    const float*  __restrict__ z_buf,
    unsigned int* __restrict__ bits,
    const float4* __restrict__ inputs4,
    const float*  __restrict__ psc_rise,
    const float*  __restrict__ psc,
    const float*  __restrict__ syn_decay,
    const float*  __restrict__ psc_initial,
    const float*  __restrict__ v,
    const float*  __restrict__ r,
    const float*  __restrict__ asc1,
    const float*  __restrict__ asc2,
    const float*  __restrict__ v_th,
    const float*  __restrict__ e_l,
    const float*  __restrict__ v_reset,
    const float*  __restrict__ g,
    const float*  __restrict__ decay,
    const float*  __restrict__ current_factor,
    const float*  __restrict__ t_ref,
    const float2* __restrict__ k,
    const float2* __restrict__ asc_amps,
    const float*  __restrict__ voltage_scale,
    const float*  __restrict__ voltage_offset,
    float*        __restrict__ out)
{
    int b = blockIdx.x;
    int tid = threadIdx.x;

    if (b < ZB_BLOCKS) {
        int i = b * 256 + tid;
        float zv = (i < DN) ? z_buf[i] : 0.0f;
        unsigned long long m = __ballot(zv != 0.0f);
        if ((tid & 63) == 0) {
            int w = i >> 5;
            bits[w]     = (unsigned int)m;
            bits[w + 1] = (unsigned int)(m >> 32);
        }
        return;
    }
    b -= ZB_BLOCKS;
    if (b < SEED_BLOCKS) {
        int j = b * 256 + tid;
        if (j >= RN / 4) return;
        const float4* pr4 = reinterpret_cast<const float4*>(psc_rise);
        const float4* ps4 = reinterpret_cast<const float4*>(psc);
        const float4* sd4 = reinterpret_cast<const float4*>(syn_decay);
        const float4* pi4 = reinterpret_cast<const float4*>(psc_initial);
        float4* opr4 = reinterpret_cast<float4*>(out + 11 * N);
        float4* ops4 = reinterpret_cast<float4*>(out + 21 * N);
        float4 sd = sd4[j];
        float4 pr = pr4[j];
        float4 pi = pi4[j];
        float4 in = inputs4[j];
        float4 ps = ps4[j];
        float4 opr, ops;
        opr.x = sd.x * pr.x + in.x * pi.x;
        opr.y = sd.y * pr.y + in.y * pi.y;
        opr.z = sd.z * pr.z + in.z * pi.z;
        opr.w = sd.w * pr.w + in.w * pi.w;
        ops.x = ps.x * sd.x + sd.x * pr.x;
        ops.y = ps.y * sd.y + sd.y * pr.y;
        ops.z = ps.z * sd.z + sd.z * pr.z;
        ops.w = ps.w * sd.w + sd.w * pr.w;
        opr4[j] = opr;
        ops4[j] = ops;
        return;
    }
    b -= SEED_BLOCKS;
    {
        int n = b * 256 + tid;
        if (n >= N) return;

        float prev_z = z_buf[n];

        const float2* p2 = reinterpret_cast<const float2*>(psc + n * R);
        float ic = 0.0f;
#pragma unroll
        for (int t = 0; t < R / 2; ++t) {
            float2 pp = p2[t];
            ic += pp.x + pp.y;
        }

        float new_r = fmaxf(r[n] + prev_z * t_ref[n] - 1.0f, 0.0f);   // DT=1

        float2 kk = k[n];
        float2 aa = asc_amps[n];
        float s0 = 1.0f / (1.0f + expf(-kk.x));
        float s1 = 1.0f / (1.0f + expf(-kk.y));
        float a1_old = asc1[n];
        float a2_old = asc2[n];
        float new_a1 = expf(-s0) * a1_old + prev_z * aa.x;
        float new_a2 = expf(-s1) * a2_old + prev_z * aa.y;

        float el = e_l[n];
        float new_v = decay[n] * v[n]
                    + current_factor[n] * (ic + a1_old + a2_old + g[n] * el);

        float vth = v_th[n];
        float v_sc = (new_v - vth) / (vth - el);
        float nz = (v_sc > 0.0f) ? 1.0f : 0.0f;
        if (new_r > 0.0f) nz = 0.0f;
        if (nz > 0.5f) new_v = v_reset[n];

        out[0 * N + n]  = nz;
        out[1 * N + n]  = new_v * voltage_scale[n] + voltage_offset[n];
        out[2 * N + n]  = nz;
        out[7 * N + n]  = new_v;
        out[8 * N + n]  = new_r;
        out[9 * N + n]  = new_a1;
        out[10 * N + n] = new_a2;
    }
}

// ---------------------------------------------------------------------------
// K2: streaming scatter with ONE-ITERATION DEFERRED COMMIT.
// iter t: load idx4 (stream), commit iter t-1's pending atomics (their
// gathers have had the bit-test + loop-turn to complete), test bits, issue
// this iter's predicated gathers into registers.
__global__ __launch_bounds__(SC_BLOCK) void scatter_kernel(
    const float* __restrict__ rec_w,
    const int4*  __restrict__ idx4,          // [p] = (row0, col0, row1, col1)
    const unsigned int* __restrict__ bits_g,
    const float* __restrict__ pinit,
    const float* __restrict__ z_buf,
    float*       __restrict__ out)
{
    __shared__ unsigned int bits[ZB_WORDS];
    {
        const uint4* src = reinterpret_cast<const uint4*>(bits_g);
        uint4* dst = reinterpret_cast<uint4*>(bits);
        for (int i = threadIdx.x; i < ZB_WORDS / 4; i += SC_BLOCK)
            dst[i] = src[i];
    }
    __syncthreads();

    float* opr = out + 11 * N;
    const int gid = blockIdx.x * SC_BLOCK + threadIdx.x;

    bool  v0 = false, v1 = false;     // pending-commit state (prev iter)
    int   r0 = 0, r1 = 0;
    float w0 = 0.f, w1 = 0.f, q0 = 0.f, q1 = 0.f;

    for (int p = gid; p < EP; p += GS) {
        int4 a = idx4[p];             // stream load issues first

        // commit previous iteration's actives
        if (v0) atomicAdd(opr + r0, w0 * q0);
        if (v1) atomicAdd(opr + r1, w1 * q1);

        bool a0 = (bits[a.y >> 5] >> (a.y & 31)) & 1u;
        bool a1 = (bits[a.w >> 5] >> (a.w & 31)) & 1u;
        r0 = a.x; r1 = a.z;
        if (a0) { w0 = rec_w[2 * p];     q0 = pinit[a.x]; }
        if (a1) { w1 = rec_w[2 * p + 1]; q1 = pinit[a.z]; }
        v0 = a0; v1 = a1;
    }
    // drain
    if (v0) atomicAdd(opr + r0, w0 * q0);
    if (v1) atomicAdd(opr + r1, w1 * q1);

    // tail: delay-buffer shift (independent of scatter results)
    {
        const float4* src = reinterpret_cast<const float4*>(z_buf);
        float4* dst = reinterpret_cast<float4*>(out + 3 * N);
        for (int i = gid; i < (DN - N) / 4; i += GS)
            dst[i] = src[i];
    }
}

} // namespace

extern "C" void kernel_launch(void* const* d_in, const int* in_sizes, int n_in,
                              void* d_out, int out_size, void* d_ws, size_t ws_size,
                              hipStream_t stream) {
    const float* inputs         = (const float*)d_in[0];
    const float* z_buf          = (const float*)d_in[1];
    const float* v              = (const float*)d_in[2];
    const float* r              = (const float*)d_in[3];
    const float* asc1           = (const float*)d_in[4];
    const float* asc2           = (const float*)d_in[5];
    const float* psc_rise       = (const float*)d_in[6];
    const float* psc            = (const float*)d_in[7];
    const float* rec_w          = (const float*)d_in[8];
    const int*   rec_idx        = (const int*)d_in[9];
    const float* v_th           = (const float*)d_in[10];
    const float* e_l            = (const float*)d_in[11];
    const float* v_reset        = (const float*)d_in[12];
    const float* g              = (const float*)d_in[13];
    const float* decay          = (const float*)d_in[14];
    const float* current_factor = (const float*)d_in[15];
    const float* t_ref          = (const float*)d_in[16];
    const float* k              = (const float*)d_in[17];
    const float* asc_amps       = (const float*)d_in[18];
    const float* syn_decay      = (const float*)d_in[19];
    const float* psc_initial    = (const float*)d_in[20];
    const float* voltage_scale  = (const float*)d_in[21];
    const float* voltage_offset = (const float*)d_in[22];

    float* out = (float*)d_out;
    unsigned int* bits = (unsigned int*)d_ws;          // ZB_WORDS u32

    // K1: bits + seeded psc outputs + neuron (all scatter-independent)
    pre_kernel<<<PRE_BLOCKS, 256, 0, stream>>>(
        z_buf, bits, (const float4*)inputs, psc_rise, psc, syn_decay,
        psc_initial, v, r, asc1, asc2, v_th, e_l, v_reset, g, decay,
        current_factor, t_ref, (const float2*)k, (const float2*)asc_amps,
        voltage_scale, voltage_offset, out);

    // K2: deferred-commit streaming scatter (+ shift tail)
    scatter_kernel<<<SC_GRID, SC_BLOCK, 0, stream>>>(
        rec_w, (const int4*)rec_idx, bits, psc_initial, z_buf, out);
}